// Round 1
// baseline (1009.276 us; speedup 1.0000x reference)
//
#include <hip/hip_runtime.h>

// Problem constants
#define BATCH 16
#define NROW  10647
#define ROWF  85          // 4 box + 1 obj + 80 cls
#define NCLS  80
#define KTOP  2048
#define MPAD  16384       // next pow2 >= NROW
#define NTILE 128         // MPAD / 128 rows per tile
#define SCORE_THR 0.5f
#define IOU_THR   0.5f

typedef unsigned long long u64;
typedef unsigned int u32;

__device__ __forceinline__ u32 enc_f32(float f) {
    u32 u = __float_as_uint(f);
    return (u & 0x80000000u) ? ~u : (u | 0x80000000u);
}
__device__ __forceinline__ float dec_f32(u32 e) {
    u32 u = (e & 0x80000000u) ? (e & 0x7FFFFFFFu) : ~e;
    return __uint_as_float(u);
}

// ---------------------------------------------------------------------------
// Kernel 1: scores -> sortable u64 keys.  key = enc(score)<<32 | (~idx)
// grid: (128 tiles, BATCH), block: 256.  Tiles >= 84 emit padding (key=0).
// ---------------------------------------------------------------------------
__global__ void score_kernel(const float* __restrict__ yp, u64* __restrict__ keys) {
    __shared__ float tile[128 * ROWF];   // 43520 B
    const int tileIdx = blockIdx.x;
    const int b = blockIdx.y;
    const int tid = threadIdx.x;
    const int batch_lim = NROW * ROWF;
    const int tile_base = tileIdx * 128 * ROWF;

    if (tile_base < batch_lim) {
        const float* src = yp + (long long)b * batch_lim;
        for (int e = tid; e < 128 * ROWF; e += 256) {
            float v = 0.f;
            if (tile_base + e < batch_lim) v = src[tile_base + e];
            tile[e] = v;
        }
    }
    __syncthreads();

    if (tid < 128) {
        int gr = tileIdx * 128 + tid;          // < MPAD always
        u64 key = 0ULL;
        if (gr < NROW) {
            const float* r = &tile[tid * ROWF];
            float obj = r[4];
            float m = r[5];
            #pragma unroll
            for (int c = 1; c < NCLS; ++c) m = fmaxf(m, r[5 + c]);
            float s = obj * m;
            key = ((u64)enc_f32(s) << 32) | (u64)(0xFFFFFFFFu - (u32)gr);
        }
        keys[(long long)b * MPAD + gr] = key;
    }
}

// ---------------------------------------------------------------------------
// Kernel 2: per-batch full bitonic sort (descending) of MPAD u64 keys in LDS,
// then emit top-K corners/area/score SoA.  grid: BATCH, block: 1024,
// dynamic LDS: MPAD*8 = 128 KiB.
// ---------------------------------------------------------------------------
__global__ void sort_kernel(const float* __restrict__ yp,
                            const u64* __restrict__ keys,
                            float* __restrict__ sx1, float* __restrict__ sy1,
                            float* __restrict__ sx2, float* __restrict__ sy2,
                            float* __restrict__ sar, float* __restrict__ ssc) {
    extern __shared__ u64 sk[];          // MPAD entries
    const int b = blockIdx.x;
    const int tid = threadIdx.x;

    for (int t = tid; t < MPAD; t += 1024) sk[t] = keys[(long long)b * MPAD + t];
    __syncthreads();

    for (int k = 2; k <= MPAD; k <<= 1) {
        for (int j = k >> 1; j > 0; j >>= 1) {
            for (int t = tid; t < MPAD; t += 1024) {
                int ixj = t ^ j;
                if (ixj > t) {
                    u64 a = sk[t], c = sk[ixj];
                    bool up = ((t & k) == 0);
                    // descending overall
                    bool sw = up ? (a < c) : (a > c);
                    if (sw) { sk[t] = c; sk[ixj] = a; }
                }
            }
            __syncthreads();
        }
    }

    for (int t = tid; t < KTOP; t += 1024) {
        u64 key = sk[t];
        float s = dec_f32((u32)(key >> 32));
        u32 idx = 0xFFFFFFFFu - (u32)(key & 0xFFFFFFFFu);
        const float* r = yp + (long long)b * NROW * ROWF + (long long)idx * ROWF;
        float x = r[0], y = r[1], w = r[2], h = r[3];
        float hx = w * 0.5f, hy = h * 0.5f;
        float a1 = x - hx, b1 = y - hy, a2 = x + hx, b2 = y + hy;
        int o = b * KTOP + t;
        sx1[o] = a1; sy1[o] = b1; sx2[o] = a2; sy2[o] = b2;
        sar[o] = fmaxf(a2 - a1, 0.f) * fmaxf(b2 - b1, 0.f);
        ssc[o] = s;
    }
}

// ---------------------------------------------------------------------------
// Kernel 3: pairwise suppression bitmask.  mask[b][i][jb] bit jj set iff
// j = jb*64+jj > i  and  IoU(i,j) > thr.
// grid: (32 row-blocks, BATCH), block: 256.
// ---------------------------------------------------------------------------
__global__ void mask_kernel(const float* __restrict__ sx1, const float* __restrict__ sy1,
                            const float* __restrict__ sx2, const float* __restrict__ sy2,
                            const float* __restrict__ sar, u64* __restrict__ mask) {
    __shared__ float lx1[KTOP], ly1[KTOP], lx2[KTOP], ly2[KTOP], lar[KTOP]; // 40 KiB
    const int rb = blockIdx.x;
    const int b = blockIdx.y;
    const int tid = threadIdx.x;

    for (int t = tid; t < KTOP; t += 256) {
        int o = b * KTOP + t;
        lx1[t] = sx1[o]; ly1[t] = sy1[o]; lx2[t] = sx2[o]; ly2[t] = sy2[o]; lar[t] = sar[o];
    }
    __syncthreads();

    for (int s = 0; s < 8; ++s) {
        int task = tid + s * 256;          // 0..2047
        int li = task >> 5;                // 0..63
        int jb = task & 31;                // 0..31
        int i = rb * 64 + li;
        float ax1 = lx1[i], ay1 = ly1[i], ax2 = lx2[i], ay2 = ly2[i], aa = lar[i];
        u64 bits = 0ULL;
        int jbase = jb * 64;
        for (int jj = 0; jj < 64; ++jj) {
            int j = jbase + jj;
            if (j > i) {
                float ix1 = fmaxf(ax1, lx1[j]);
                float iy1 = fmaxf(ay1, ly1[j]);
                float ix2 = fminf(ax2, lx2[j]);
                float iy2 = fminf(ay2, ly2[j]);
                float inter = fmaxf(ix2 - ix1, 0.f) * fmaxf(iy2 - iy1, 0.f);
                float uni = aa + lar[j] - inter;
                float iou = inter / fmaxf(uni, 1e-9f);
                if (iou > IOU_THR) bits |= (1ULL << jj);
            }
        }
        mask[((long long)(b * KTOP + i)) * 32 + jb] = bits;
    }
}

// ---------------------------------------------------------------------------
// Kernel 4: serial greedy reduce over the mask + final masked output write.
// grid: BATCH, block: 256.  Lanes 0..31 of wave 0 hold the 2048 keep bits.
// ---------------------------------------------------------------------------
__global__ void nms_out_kernel(const float* __restrict__ sx1, const float* __restrict__ sy1,
                               const float* __restrict__ sx2, const float* __restrict__ sy2,
                               const float* __restrict__ ssc,
                               const u64* __restrict__ mask, float* __restrict__ out) {
    __shared__ u64 cm[128 * 32];   // 32 KiB chunk of mask rows
    __shared__ u64 keepw[32];
    const int b = blockIdx.x;
    const int tid = threadIdx.x;

    // init keep = valid (score > thr)
    if (tid < 32) {
        u64 bits = 0ULL;
        for (int jj = 0; jj < 64; ++jj)
            if (ssc[b * KTOP + tid * 64 + jj] > SCORE_THR) bits |= (1ULL << jj);
        keepw[tid] = bits;
    }
    __syncthreads();

    u64 myw = (tid < 32) ? keepw[tid] : 0ULL;

    for (int c = 0; c < 16; ++c) {            // 16 chunks x 128 rows
        const u64* src = mask + ((long long)(b * KTOP + c * 128)) * 32;
        for (int t = tid; t < 128 * 32; t += 256) cm[t] = src[t];
        __syncthreads();
        if (tid < 32) {
            for (int sb = 0; sb < 2; ++sb) {
                int w = c * 2 + sb;           // word-block index of these 64 rows
                u64 cur = __shfl(myw, w);     // current keep word for rows in this block
                for (int bit = 0; bit < 64; ++bit) {
                    if ((cur >> bit) & 1ULL) {
                        int li = sb * 64 + bit;
                        u64 mrow = cm[li * 32 + tid];   // per-lane word
                        u64 mv   = cm[li * 32 + w];     // broadcast: this block's word
                        myw &= ~mrow;
                        cur &= ~mv;
                    }
                }
            }
        }
        __syncthreads();
    }

    if (tid < 32) keepw[tid] = myw;
    __syncthreads();

    for (int t = tid; t < KTOP; t += 256) {
        int o = b * KTOP + t;
        float f = ((keepw[t >> 6] >> (t & 63)) & 1ULL) ? 1.0f : 0.0f;
        float* op = out + (long long)o * 5;
        op[0] = sx1[o] * f;
        op[1] = sy1[o] * f;
        op[2] = sx2[o] * f;
        op[3] = sy2[o] * f;
        op[4] = ssc[o] * f;
    }
}

// ---------------------------------------------------------------------------
extern "C" void kernel_launch(void* const* d_in, const int* in_sizes, int n_in,
                              void* d_out, int out_size, void* d_ws, size_t ws_size,
                              hipStream_t stream) {
    const float* yp = (const float*)d_in[0];
    float* out = (float*)d_out;
    char* ws = (char*)d_ws;

    // workspace layout (keys region is dead before mask region is written -> alias)
    const size_t MASK_BYTES = (size_t)BATCH * KTOP * 32 * sizeof(u64);   // 8 MiB
    u64* keys = (u64*)ws;                       // BATCH*MPAD*8 = 2 MiB (aliased under mask)
    u64* mask = (u64*)ws;
    float* soa = (float*)(ws + MASK_BYTES);     // 6 arrays of BATCH*KTOP floats
    const int SA = BATCH * KTOP;
    float* sx1 = soa + 0 * SA;
    float* sy1 = soa + 1 * SA;
    float* sx2 = soa + 2 * SA;
    float* sy2 = soa + 3 * SA;
    float* sar = soa + 4 * SA;
    float* ssc = soa + 5 * SA;

    dim3 g1(NTILE, BATCH);
    score_kernel<<<g1, 256, 0, stream>>>(yp, keys);

    sort_kernel<<<BATCH, 1024, MPAD * sizeof(u64), stream>>>(yp, keys, sx1, sy1, sx2, sy2, sar, ssc);

    dim3 g3(32, BATCH);
    mask_kernel<<<g3, 256, 0, stream>>>(sx1, sy1, sx2, sy2, sar, mask);

    nms_out_kernel<<<BATCH, 256, 0, stream>>>(sx1, sy1, sx2, sy2, ssc, mask, out);
}

// Round 2
// 385.256 us; speedup vs baseline: 2.6198x; 2.6198x over previous
//
#include <hip/hip_runtime.h>

// Problem constants
#define BATCH 16
#define NROW  10647
#define ROWF  85          // 4 box + 1 obj + 80 cls
#define NCLS  80
#define KTOP  2048
#define MPAD  16384       // next pow2 >= NROW
#define SCORE_THR 0.5f
#define IOU_THR   0.5f

typedef unsigned long long u64;
typedef unsigned int u32;

__device__ __forceinline__ u32 enc_f32(float f) {
    u32 u = __float_as_uint(f);
    return (u & 0x80000000u) ? ~u : (u | 0x80000000u);
}
__device__ __forceinline__ float dec_f32(u32 e) {
    u32 u = (e & 0x80000000u) ? (e & 0x7FFFFFFFu) : ~e;
    return __uint_as_float(u);
}
__device__ __forceinline__ float bcast(float v, int ii) {
    return __uint_as_float(__builtin_amdgcn_readlane(__float_as_uint(v), ii));
}

// ---------------------------------------------------------------------------
// Kernel 1: scores -> sortable u64 keys.  key = enc(score)<<32 | (~idx)
// grid: (128 tiles, BATCH), block: 256.  Rows >= NROW emit key=0.
// ---------------------------------------------------------------------------
__global__ void score_kernel(const float* __restrict__ yp, u64* __restrict__ keys) {
    __shared__ float tile[128 * ROWF];   // 43520 B
    const int tileIdx = blockIdx.x;
    const int b = blockIdx.y;
    const int tid = threadIdx.x;
    const int batch_lim = NROW * ROWF;
    const int tile_base = tileIdx * 128 * ROWF;

    if (tile_base < batch_lim) {
        const float* src = yp + (long long)b * batch_lim;
        for (int e = tid; e < 128 * ROWF; e += 256) {
            float v = 0.f;
            if (tile_base + e < batch_lim) v = src[tile_base + e];
            tile[e] = v;
        }
    }
    __syncthreads();

    if (tid < 128) {
        int gr = tileIdx * 128 + tid;          // < MPAD always
        u64 key = 0ULL;
        if (gr < NROW) {
            const float* r = &tile[tid * ROWF];
            float obj = r[4];
            float m = r[5];
            #pragma unroll
            for (int c = 1; c < NCLS; ++c) m = fmaxf(m, r[5 + c]);
            float s = obj * m;
            key = ((u64)enc_f32(s) << 32) | (u64)(0xFFFFFFFFu - (u32)gr);
        }
        keys[(long long)b * MPAD + gr] = key;
    }
}

// ---------------------------------------------------------------------------
// Kernel 2a: sort each 2048-chunk descending (chunks 0..5 cover all real rows;
// chunks 6,7 are all-zero keys and are skipped). grid (6, BATCH), block 256.
// ---------------------------------------------------------------------------
__global__ void chunk_sort_kernel(u64* __restrict__ keys) {
    __shared__ u64 sm[2048];   // 16 KiB
    const int b = blockIdx.y, c = blockIdx.x, tid = threadIdx.x;
    u64* base = keys + (long long)b * MPAD + c * 2048;
    for (int t = tid; t < 2048; t += 256) sm[t] = base[t];
    __syncthreads();
    for (int k = 2; k <= 2048; k <<= 1) {
        for (int j = k >> 1; j > 0; j >>= 1) {
            for (int t = tid; t < 2048; t += 256) {
                int ixj = t ^ j;
                if (ixj > t) {
                    u64 a = sm[t], cc = sm[ixj];
                    bool up = ((t & k) == 0);
                    if (up ? (a < cc) : (a > cc)) { sm[t] = cc; sm[ixj] = a; }
                }
            }
            __syncthreads();
        }
    }
    for (int t = tid; t < 2048; t += 256) base[t] = sm[t];
}

// Half-cleaner top-2048 of two descending 2048-seqs, then bitonic cleanup.
__device__ __forceinline__ void merge_top2048(const u64* __restrict__ a,
                                              const u64* __restrict__ bseq,
                                              u64* sm, int tid) {
    for (int t = tid; t < 2048; t += 256) {
        u64 va = a[t], vb = bseq[2047 - t];
        sm[t] = va > vb ? va : vb;
    }
    __syncthreads();
    for (int j = 1024; j > 0; j >>= 1) {
        for (int t = tid; t < 2048; t += 256) {
            int ixj = t ^ j;
            if (ixj > t) {
                u64 x = sm[t], y = sm[ixj];
                if (x < y) { sm[t] = y; sm[ixj] = x; }
            }
        }
        __syncthreads();
    }
}

// Kernel 2b: round 1 — (0,1)->B0, (2,3)->B1, (4,5)->B2. grid (3, BATCH).
__global__ void merge_r1_kernel(const u64* __restrict__ keysA, u64* __restrict__ keysB) {
    __shared__ u64 sm[2048];
    const int b = blockIdx.y, c = blockIdx.x, tid = threadIdx.x;
    const u64* a = keysA + (long long)b * MPAD + c * 4096;
    merge_top2048(a, a + 2048, sm, tid);
    u64* d = keysB + (long long)b * MPAD + c * 2048;
    for (int t = tid; t < 2048; t += 256) d[t] = sm[t];
}

// Kernel 2c: round 2 — (B0,B1)->A0. grid (BATCH).
__global__ void merge_r2_kernel(const u64* __restrict__ keysB, u64* __restrict__ keysA) {
    __shared__ u64 sm[2048];
    const int b = blockIdx.x, tid = threadIdx.x;
    const u64* a = keysB + (long long)b * MPAD;
    merge_top2048(a, a + 2048, sm, tid);
    u64* d = keysA + (long long)b * MPAD;
    for (int t = tid; t < 2048; t += 256) d[t] = sm[t];
}

// Kernel 2d: round 3 — (A0,B2)->final top-2048, fused gather of corners/area.
__global__ void merge_r3_gather_kernel(const u64* __restrict__ keysA,
                                       const u64* __restrict__ keysB,
                                       const float* __restrict__ yp,
                                       float* __restrict__ sx1, float* __restrict__ sy1,
                                       float* __restrict__ sx2, float* __restrict__ sy2,
                                       float* __restrict__ sar, float* __restrict__ ssc) {
    __shared__ u64 sm[2048];
    const int b = blockIdx.x, tid = threadIdx.x;
    merge_top2048(keysA + (long long)b * MPAD, keysB + (long long)b * MPAD + 4096, sm, tid);

    for (int t = tid; t < KTOP; t += 256) {
        u64 key = sm[t];
        float s = dec_f32((u32)(key >> 32));
        u32 idx = 0xFFFFFFFFu - (u32)(key & 0xFFFFFFFFu);
        const float* r = yp + (long long)b * NROW * ROWF + (long long)idx * ROWF;
        float x = r[0], y = r[1], w = r[2], h = r[3];
        float hx = w * 0.5f, hy = h * 0.5f;
        float a1 = x - hx, b1 = y - hy, a2 = x + hx, b2 = y + hy;
        int o = b * KTOP + t;
        sx1[o] = a1; sy1[o] = b1; sx2[o] = a2; sy2[o] = b2;
        sar[o] = fmaxf(a2 - a1, 0.f) * fmaxf(b2 - b1, 0.f);
        ssc[o] = s;
    }
}

// ---------------------------------------------------------------------------
// Kernel 3: pairwise suppression bitmask, 64x64 wave tiles, upper triangle
// only (cb >= rb).  Lane holds its column box in registers; row box broadcast
// via readlane; one __ballot per row.  grid (132, BATCH), block 256 (4 waves).
// ---------------------------------------------------------------------------
__global__ void mask_kernel(const float* __restrict__ sx1, const float* __restrict__ sy1,
                            const float* __restrict__ sx2, const float* __restrict__ sy2,
                            const float* __restrict__ sar, u64* __restrict__ mask) {
    const int b = blockIdx.y;
    const int t = blockIdx.x * 4 + (threadIdx.x >> 6);   // 0..527
    const int lane = threadIdx.x & 63;

    // decode upper-triangle tile t -> (rb, cb), cb >= rb, n = 32
    int rb = (int)((65.0f - sqrtf(4225.0f - 8.0f * (float)t)) * 0.5f);
    while (rb * (65 - rb) / 2 > t) --rb;
    while ((rb + 1) * (64 - rb) / 2 <= t) ++rb;
    const int cb = rb + t - rb * (65 - rb) / 2;

    const int oi = b * KTOP + rb * 64 + lane;
    const int oj = b * KTOP + cb * 64 + lane;
    const float rx1 = sx1[oi], ry1 = sy1[oi], rx2 = sx2[oi], ry2 = sy2[oi], ra = sar[oi];
    const float cx1 = sx1[oj], cy1 = sy1[oj], cx2 = sx2[oj], cy2 = sy2[oj], ca = sar[oj];
    const bool diag = (rb == cb);

    u64 myword = 0ULL;
    for (int ii = 0; ii < 64; ++ii) {
        float ax1 = bcast(rx1, ii), ay1 = bcast(ry1, ii);
        float ax2 = bcast(rx2, ii), ay2 = bcast(ry2, ii);
        float aa  = bcast(ra,  ii);
        float ix1 = fmaxf(ax1, cx1);
        float iy1 = fmaxf(ay1, cy1);
        float ix2 = fminf(ax2, cx2);
        float iy2 = fminf(ay2, cy2);
        float inter = fmaxf(ix2 - ix1, 0.f) * fmaxf(iy2 - iy1, 0.f);
        float uni = aa + ca - inter;
        float iou = inter / fmaxf(uni, 1e-9f);
        bool cond = (iou > IOU_THR) && (!diag || (lane > ii));
        u64 bal = __ballot(cond);
        if (lane == ii) myword = bal;
    }
    mask[(long long)(b * KTOP + rb * 64 + lane) * 32 + cb] = myword;
}

// ---------------------------------------------------------------------------
// Kernel 4: serial greedy reduce over the mask + final masked output write.
// Lower-triangle mask words were never written -> consumer zeroes them.
// grid: BATCH, block: 256.
// ---------------------------------------------------------------------------
__global__ void nms_out_kernel(const float* __restrict__ sx1, const float* __restrict__ sy1,
                               const float* __restrict__ sx2, const float* __restrict__ sy2,
                               const float* __restrict__ ssc,
                               const u64* __restrict__ mask, float* __restrict__ out) {
    __shared__ u64 cm[128 * 32];   // 32 KiB chunk of mask rows
    __shared__ u64 keepw[32];
    const int b = blockIdx.x;
    const int tid = threadIdx.x;

    if (tid < 32) {
        u64 bits = 0ULL;
        for (int jj = 0; jj < 64; ++jj)
            if (ssc[b * KTOP + tid * 64 + jj] > SCORE_THR) bits |= (1ULL << jj);
        keepw[tid] = bits;
    }
    __syncthreads();

    u64 myw = (tid < 32) ? keepw[tid] : 0ULL;

    for (int c = 0; c < 16; ++c) {            // 16 chunks x 128 rows
        const u64* src = mask + ((long long)(b * KTOP + c * 128)) * 32;
        for (int t = tid; t < 128 * 32; t += 256) cm[t] = src[t];
        __syncthreads();
        if (tid < 32) {
            for (int sb = 0; sb < 2; ++sb) {
                int w = c * 2 + sb;           // word-block index of these 64 rows
                u64 cur = __shfl(myw, w);
                for (int bit = 0; bit < 64; ++bit) {
                    if ((cur >> bit) & 1ULL) {
                        int li = sb * 64 + bit;
                        u64 mrow = (tid >= w) ? cm[li * 32 + tid] : 0ULL;  // j>i guard
                        u64 mv   = cm[li * 32 + w];
                        myw &= ~mrow;
                        cur &= ~mv;
                    }
                }
            }
        }
        __syncthreads();
    }

    if (tid < 32) keepw[tid] = myw;
    __syncthreads();

    for (int t = tid; t < KTOP; t += 256) {
        int o = b * KTOP + t;
        float f = ((keepw[t >> 6] >> (t & 63)) & 1ULL) ? 1.0f : 0.0f;
        float* op = out + (long long)o * 5;
        op[0] = sx1[o] * f;
        op[1] = sy1[o] * f;
        op[2] = sx2[o] * f;
        op[3] = sy2[o] * f;
        op[4] = ssc[o] * f;
    }
}

// ---------------------------------------------------------------------------
extern "C" void kernel_launch(void* const* d_in, const int* in_sizes, int n_in,
                              void* d_out, int out_size, void* d_ws, size_t ws_size,
                              hipStream_t stream) {
    const float* yp = (const float*)d_in[0];
    float* out = (float*)d_out;
    char* ws = (char*)d_ws;

    // Workspace layout (aliasing is safe by kernel ordering):
    //   [0, 2MiB)   keysA          (dead after merge_r3)
    //   [2, 4MiB)   keysB          (dead after merge_r3)
    //   [0, 8MiB)   mask           (written by mask_kernel, after keys die)
    //   [8MiB, +768KiB) SoA arrays (live to the end)
    const size_t KEYS_BYTES = (size_t)BATCH * MPAD * sizeof(u64);        // 2 MiB
    const size_t MASK_BYTES = (size_t)BATCH * KTOP * 32 * sizeof(u64);   // 8 MiB
    u64* keysA = (u64*)ws;
    u64* keysB = (u64*)(ws + KEYS_BYTES);
    u64* mask  = (u64*)ws;
    float* soa = (float*)(ws + MASK_BYTES);
    const int SA = BATCH * KTOP;
    float* sx1 = soa + 0 * SA;
    float* sy1 = soa + 1 * SA;
    float* sx2 = soa + 2 * SA;
    float* sy2 = soa + 3 * SA;
    float* sar = soa + 4 * SA;
    float* ssc = soa + 5 * SA;

    score_kernel<<<dim3(128, BATCH), 256, 0, stream>>>(yp, keysA);
    chunk_sort_kernel<<<dim3(6, BATCH), 256, 0, stream>>>(keysA);
    merge_r1_kernel<<<dim3(3, BATCH), 256, 0, stream>>>(keysA, keysB);
    merge_r2_kernel<<<BATCH, 256, 0, stream>>>(keysB, keysA);
    merge_r3_gather_kernel<<<BATCH, 256, 0, stream>>>(keysA, keysB, yp,
                                                      sx1, sy1, sx2, sy2, sar, ssc);
    mask_kernel<<<dim3(132, BATCH), 256, 0, stream>>>(sx1, sy1, sx2, sy2, sar, mask);
    nms_out_kernel<<<BATCH, 256, 0, stream>>>(sx1, sy1, sx2, sy2, ssc, mask, out);
}